// Round 4
// baseline (547.741 us; speedup 1.0000x reference)
//
#include <hip/hip_runtime.h>
#include <hip/hip_bf16.h>
#include <cstdint>
#include <type_traits>

typedef unsigned short u16;
typedef __attribute__((ext_vector_type(8))) short short8;
typedef __attribute__((ext_vector_type(4))) float floatx4;

__device__ __forceinline__ u16 f2bf(float f) {
  union { float f; uint32_t u; } v; v.f = f;
  uint32_t u = v.u;
  return (u16)((u + 0x7FFFu + ((u >> 16) & 1u)) >> 16);
}
__device__ __forceinline__ float bf2f(u16 h) {
  union { uint32_t u; float f; } v; v.u = ((uint32_t)h) << 16;
  return v.f;
}

// global -> LDS direct, 16B per lane. LDS dest is wave-uniform base + lane*16
// (m104); global src is per-lane. Direct addrspace casts (addrspacecast).
typedef const __attribute__((address_space(1))) char GChar;
typedef __attribute__((address_space(3))) char LChar;
__device__ __forceinline__ void gload_lds16(const void* g, void* l) {
  __builtin_amdgcn_global_load_lds((GChar*)g, (LChar*)l, 16, 0, 0);
}

// ---------------- elementwise: fp32 -> bf16 cast ----------------
__global__ void cast_f32_bf16(const float* __restrict__ src, u16* __restrict__ dst, int n) {
  int i = (blockIdx.x * blockDim.x + threadIdx.x) * 4;
  int stride = gridDim.x * blockDim.x * 4;
  for (; i < n; i += stride) {
    float4 v = *reinterpret_cast<const float4*>(src + i);
    ushort4 o;
    o.x = f2bf(v.x); o.y = f2bf(v.y); o.z = f2bf(v.z); o.w = f2bf(v.w);
    *reinterpret_cast<ushort4*>(dst + i) = o;
  }
}

// ---------------- RoPE tables (matches reference: theta=10000^(-2(i-1)/D)) --
__global__ void rope_tables(float* __restrict__ cosT, float* __restrict__ sinT) {
  int idx = blockIdx.x * blockDim.x + threadIdx.x;   // m*512 + i
  int m = idx >> 9;
  int i = idx & 511;
  double ex = -2.0 * ((double)i - 1.0) / 1024.0;
  double theta = exp(ex * log(10000.0));
  double ang = (double)m * theta;
  cosT[idx] = (float)cos(ang);
  sinT[idx] = (float)sin(ang);
}

// ---------------- GEMM-BT: C[i][j] = scale * sum_k A[i][k]*W[j][k] ---------
// A,W bf16 row-major; C fp32 or bf16. 128x128 tile, BK=32, 4 waves (2x2 of 64x64),
// mfma_f32_16x16x32_bf16, global_load_lds width-16 staging (m97 structure).
template <typename CT>
__global__ __launch_bounds__(256) void gemm_bt(
    const u16* __restrict__ A, const u16* __restrict__ Bw, CT* __restrict__ C,
    int K, long lda, long ldb, long ldc,
    long strideA, long strideB, long strideC, float scale)
{
  __shared__ u16 As[128 * 32];
  __shared__ u16 Bs[128 * 32];

  const int bz = blockIdx.z;
  A  += (long)bz * strideA;
  Bw += (long)bz * strideB;
  C  += (long)bz * strideC;

  const int tm = blockIdx.y, tn = blockIdx.x;
  const int t = threadIdx.x;
  const int lane = t & 63, wave = t >> 6;
  const int wm = (wave >> 1) * 64, wn = (wave & 1) * 64;

  // staging: thread t covers LDS elements t*8..t*8+7 => row t/4, col (t%4)*8
  const int srow = t >> 2;
  const int scol = (t & 3) * 8;
  const u16* Ag = A + (long)(tm * 128 + srow) * lda + scol;
  const u16* Bg = Bw + (long)(tn * 128 + srow) * ldb + scol;
  u16* AsW = As + wave * 512;   // wave-uniform LDS base (lane lands at +lane*8)
  u16* BsW = Bs + wave * 512;

  floatx4 acc[4][4];
#pragma unroll
  for (int m = 0; m < 4; ++m)
#pragma unroll
    for (int n = 0; n < 4; ++n) acc[m][n] = (floatx4){0.f, 0.f, 0.f, 0.f};

  const int arow = (lane & 15) * 32 + ((lane >> 4) * 8);  // frag offset: row*32+k
  const int nk = K >> 5;
  for (int kt = 0; kt < nk; ++kt) {
    __syncthreads();  // previous tile fully consumed
    const u16* ag = Ag + kt * 32;
    const u16* bg = Bg + kt * 32;
    gload_lds16(ag,             AsW);
    gload_lds16(ag + 64 * lda,  AsW + 2048);
    gload_lds16(bg,             BsW);
    gload_lds16(bg + 64 * ldb,  BsW + 2048);
    __syncthreads();  // drains vmcnt -> tile ready

    short8 af[4], bf[4];
#pragma unroll
    for (int m = 0; m < 4; ++m)
      af[m] = *reinterpret_cast<const short8*>(&As[(wm + m * 16) * 32 + arow]);
#pragma unroll
    for (int n = 0; n < 4; ++n)
      bf[n] = *reinterpret_cast<const short8*>(&Bs[(wn + n * 16) * 32 + arow]);
#pragma unroll
    for (int m = 0; m < 4; ++m)
#pragma unroll
      for (int n = 0; n < 4; ++n)
        acc[m][n] = __builtin_amdgcn_mfma_f32_16x16x32_bf16(af[m], bf[n], acc[m][n], 0, 0, 0);
  }

  // epilogue: C/D layout col=lane&15, row=(lane>>4)*4+r (m89/m91 verified)
  const long crow = (long)tm * 128 + wm + ((lane >> 4) << 2);
  const long ccol = (long)tn * 128 + wn + (lane & 15);
#pragma unroll
  for (int m = 0; m < 4; ++m)
#pragma unroll
    for (int n = 0; n < 4; ++n)
#pragma unroll
      for (int r = 0; r < 4; ++r) {
        long row = crow + m * 16 + r;
        long col = ccol + n * 16;
        float val = acc[m][n][r] * scale;
        if constexpr (std::is_same<CT, u16>::value)
          C[row * ldc + col] = f2bf(val);
        else
          C[row * ldc + col] = val;
      }
}

// ---------------- RoPE in-place on Q,K halves of qkv cat --------------------
__global__ void rope_apply(u16* __restrict__ qkv,
                           const float* __restrict__ cosT, const float* __restrict__ sinT) {
  int g = blockIdx.x * blockDim.x + threadIdx.x;   // 16384 rows * 128 groups
  int row = g >> 7;
  int grp = g & 127;
  int m = row & 2047;
  int p0 = grp * 4;  // 4 pairs = 8 contiguous bf16
  float4 c = *reinterpret_cast<const float4*>(&cosT[m * 512 + p0]);
  float4 s = *reinterpret_cast<const float4*>(&sinT[m * 512 + p0]);
  float cc[4] = {c.x, c.y, c.z, c.w};
  float ss[4] = {s.x, s.y, s.z, s.w};
  long base = (long)row * 3072 + p0 * 2;
#pragma unroll
  for (int h = 0; h < 2; ++h) {   // h=0: Q, h=1: K (+1024)
    u16* p = qkv + base + h * 1024;
    short8 v = *reinterpret_cast<const short8*>(p);
    short8 o;
#pragma unroll
    for (int j = 0; j < 4; ++j) {
      float te = bf2f((u16)v[2 * j]);
      float to = bf2f((u16)v[2 * j + 1]);
      float re = te * cc[j] + to * ss[j];
      float ro = -te * ss[j] + to * cc[j];
      o[2 * j] = (short)f2bf(re);
      o[2 * j + 1] = (short)f2bf(ro);
    }
    *reinterpret_cast<short8*>(p) = o;
  }
}

// ---------------- V transpose: vt[b][d][m] = V[b][m][d] ---------------------
__global__ void transpose_v(const u16* __restrict__ qkv, u16* __restrict__ vt) {
  __shared__ u16 tile[32][33];
  int b = blockIdx.z;
  int m0 = blockIdx.y * 32, d0 = blockIdx.x * 32;
  int tx = threadIdx.x & 31, ty = threadIdx.x >> 5;  // 32x8
#pragma unroll
  for (int r = ty; r < 32; r += 8)
    tile[r][tx] = qkv[(long)(b * 2048 + m0 + r) * 3072 + 2048 + d0 + tx];
  __syncthreads();
#pragma unroll
  for (int r = ty; r < 32; r += 8)
    vt[(long)b * 1024 * 2048 + (long)(d0 + r) * 2048 + m0 + tx] = tile[tx][r];
}

// ------------- row softmax on bf16 scores, P bf16 written in place ----------
__global__ __launch_bounds__(256) void softmax_rows_bf16(u16* __restrict__ S) {
  const long base = (long)blockIdx.x * 2048;
  const int t = threadIdx.x, lane = t & 63, wave = t >> 6;
  short8 in8 = *reinterpret_cast<const short8*>(&S[base + t * 8]);
  float v[8];
#pragma unroll
  for (int j = 0; j < 8; ++j) v[j] = bf2f((u16)in8[j]);
  float mx = v[0];
#pragma unroll
  for (int j = 1; j < 8; ++j) mx = fmaxf(mx, v[j]);
#pragma unroll
  for (int o = 32; o; o >>= 1) mx = fmaxf(mx, __shfl_xor(mx, o, 64));
  __shared__ float redm[4], reds[4];
  if (lane == 0) redm[wave] = mx;
  __syncthreads();
  mx = fmaxf(fmaxf(redm[0], redm[1]), fmaxf(redm[2], redm[3]));
  float sm = 0.f;
#pragma unroll
  for (int j = 0; j < 8; ++j) { v[j] = __expf(v[j] - mx); sm += v[j]; }
#pragma unroll
  for (int o = 32; o; o >>= 1) sm += __shfl_xor(sm, o, 64);
  if (lane == 0) reds[wave] = sm;
  __syncthreads();
  float inv = 1.0f / (reds[0] + reds[1] + reds[2] + reds[3]);
  short8 o8;
#pragma unroll
  for (int j = 0; j < 8; ++j) o8[j] = (short)f2bf(v[j] * inv);
  *reinterpret_cast<short8*>(&S[base + t * 8]) = o8;
}

extern "C" void kernel_launch(void* const* d_in, const int* in_sizes, int n_in,
                              void* d_out, int out_size, void* d_ws, size_t ws_size,
                              hipStream_t stream) {
  const float* x  = (const float*)d_in[0];
  const float* wq = (const float*)d_in[1];
  const float* wk = (const float*)d_in[2];
  const float* wv = (const float*)d_in[3];
  float* out = (float*)d_out;
  char* ws = (char*)d_ws;

  // workspace layout (bytes); vt overlays xb (dead after projection GEMM)
  u16*  xb   = (u16*)(ws);                          //  33,554,432  x bf16 [16384][1024]
  u16*  vt   = (u16*)(ws);                          //  33,554,432  [8][1024][2048] (after xb dead)
  u16*  wcat = (u16*)(ws + 33554432);               //   6,291,456  [wq;wk;wv] bf16 [3072][1024]
  float* cosT = (float*)(ws + 39845888);            //   4,194,304  [2048][512]
  float* sinT = (float*)(ws + 44040192);            //   4,194,304
  u16*  qkv  = (u16*)(ws + 48234496);               // 100,663,296  [16384][3072] bf16 (Q|K|V)
  u16*  S    = (u16*)(ws + 148897792);              //  67,108,864  [8][2048][2048] bf16 (P in place)
  const size_t NEED = 216006656;                    // 216.0 MB total
  if (ws_size < NEED) return;  // diagnostic guard: clean absmax fail, not a GPU fault

  cast_f32_bf16<<<2048, 256, 0, stream>>>(x, xb, 16384 * 1024);
  cast_f32_bf16<<<256, 256, 0, stream>>>(wq, wcat, 1024 * 1024);
  cast_f32_bf16<<<256, 256, 0, stream>>>(wk, wcat + 1024 * 1024, 1024 * 1024);
  cast_f32_bf16<<<256, 256, 0, stream>>>(wv, wcat + 2 * 1024 * 1024, 1024 * 1024);
  rope_tables<<<(2048 * 512) / 256, 256, 0, stream>>>(cosT, sinT);

  // QKV projection: [16384][1024] @ [3072][1024]^T -> [16384][3072] bf16
  gemm_bt<u16><<<dim3(24, 128, 1), 256, 0, stream>>>(
      xb, wcat, qkv, 1024, 1024, 1024, 3072, 0, 0, 0, 1.0f);

  rope_apply<<<(16384 * 128) / 256, 256, 0, stream>>>(qkv, cosT, sinT);
  transpose_v<<<dim3(32, 64, 8), 256, 0, stream>>>(qkv, vt);   // xb region now dead

  // scores: per batch Qr[2048][1024] @ Kr^T -> S bf16, scale 1/sqrt(1024)
  gemm_bt<u16><<<dim3(16, 16, 8), 256, 0, stream>>>(
      qkv, qkv + 1024, S, 1024, 3072, 3072, 2048,
      2048L * 3072, 2048L * 3072, 2048L * 2048, 0.03125f);

  softmax_rows_bf16<<<16384, 256, 0, stream>>>(S);

  // out: per batch P[2048][2048] bf16 @ Vt^T[1024][2048] -> fp32
  gemm_bt<float><<<dim3(8, 16, 8), 256, 0, stream>>>(
      S, vt, out, 2048, 2048, 2048, 1024,
      2048L * 2048, 1024L * 2048, 2048L * 1024, 1.0f);
}